// Round 1
// 980.619 us; speedup vs baseline: 1.0092x; 1.0092x over previous
//
#include <hip/hip_runtime.h>
#include <stdint.h>

#define M_DIM 8192
#define N_DIM 4096
#define K_DIM 4096

typedef __attribute__((ext_vector_type(4))) int i32x4;   // i8 MFMA A/B frag (16 i8) and C/D (4 i32)

// ---------- helpers ----------
__device__ __forceinline__ unsigned fkey(float f) {
  unsigned u = __float_as_uint(f);
  return (u & 0x80000000u) ? ~u : (u | 0x80000000u);
}
__device__ __forceinline__ float finv(unsigned k) {
  return __uint_as_float((k & 0x80000000u) ? (k ^ 0x80000000u) : ~k);
}
// stats slots (all atomicMin on fkey; max stored flipped): [0]xmin [1]~xmax [2]wmin [3]~wmax [4]amin [5]~amax
__device__ __forceinline__ void async16(const void* g, void* l) {
  __builtin_amdgcn_global_load_lds(
      (const __attribute__((address_space(1))) void*)g,
      (__attribute__((address_space(3))) void*)l, 16, 0, 0);
}

// ---------- 1. fused min/max over x and w ----------
__global__ void minmax_fused(const float* __restrict__ x, const float* __restrict__ w,
                             unsigned* __restrict__ stats) {
  const bool isX = blockIdx.x < 2048;
  const float4* v4 = isX ? (const float4*)x : (const float4*)w;
  const int n4 = isX ? (M_DIM * K_DIM / 4) : (N_DIM * K_DIM / 4);
  const int bid = isX ? blockIdx.x : (blockIdx.x - 2048);
  const int nb = isX ? 2048 : 1024;
  int i0 = bid * blockDim.x + threadIdx.x;
  int stride = nb * blockDim.x;
  float vmin = 3.4e38f, vmax = -3.4e38f;
  for (int i = i0; i < n4; i += stride) {
    float4 t = v4[i];
    vmin = fminf(vmin, fminf(fminf(t.x, t.y), fminf(t.z, t.w)));
    vmax = fmaxf(vmax, fmaxf(fmaxf(t.x, t.y), fmaxf(t.z, t.w)));
  }
  unsigned kmin = fkey(vmin), kmax = ~fkey(vmax);
  #pragma unroll
  for (int off = 32; off; off >>= 1) {
    unsigned t0 = __shfl_down(kmin, (unsigned)off, 64);
    unsigned t1 = __shfl_down(kmax, (unsigned)off, 64);
    kmin = kmin < t0 ? kmin : t0;
    kmax = kmax < t1 ? kmax : t1;
  }
  if ((threadIdx.x & 63) == 0) {
    int base = isX ? 0 : 2;
    atomicMin(&stats[base + 0], kmin);
    atomicMin(&stats[base + 1], kmax);
  }
}

// ---------- 2. fused quantize, row-per-block, emits row/col sums ----------
// blocks [0,8192): x row -> A8 = q_x - 128 (i8), rowA[m] = sum_k A8
// blocks [8192,12288): w row n -> B8 = q_w (i8), R8 = round(resid*126/ws),
//                      colB[n] = sum_k B8, colR[n] = sum_k R8
__global__ void quant_fused(const float* __restrict__ x, const float* __restrict__ w,
                            const unsigned* __restrict__ stats,
                            signed char* __restrict__ A8, signed char* __restrict__ B8,
                            signed char* __restrict__ R8,
                            int* __restrict__ rowA, int* __restrict__ colB, int* __restrict__ colR) {
  __shared__ int sr[8];
  const int tid = threadIdx.x;
  const int lane = tid & 63;
  const int wv = tid >> 6;
  if (blockIdx.x < M_DIM) {
    const int row = blockIdx.x;
    const float xmin = finv(stats[0]), xmax = finv(~stats[1]);
    const float xs = (xmax - xmin) / 255.0f;
    const float xzp = rintf(0.0f - xmin / xs);
    const float4* xr = (const float4*)(x + (size_t)row * K_DIM);
    char4* ar = (char4*)(A8 + (size_t)row * K_DIM);
    int s = 0;
    #pragma unroll
    for (int i = 0; i < 4; ++i) {
      int idx = tid + i * 256;
      float4 t = xr[idx];
      int q0 = (int)(fminf(fmaxf(rintf(t.x / xs + xzp), 0.f), 255.f)) - 128;
      int q1 = (int)(fminf(fmaxf(rintf(t.y / xs + xzp), 0.f), 255.f)) - 128;
      int q2 = (int)(fminf(fmaxf(rintf(t.z / xs + xzp), 0.f), 255.f)) - 128;
      int q3 = (int)(fminf(fmaxf(rintf(t.w / xs + xzp), 0.f), 255.f)) - 128;
      char4 c4; c4.x = (signed char)q0; c4.y = (signed char)q1;
      c4.z = (signed char)q2; c4.w = (signed char)q3;
      ar[idx] = c4;
      s += q0 + q1 + q2 + q3;
    }
    #pragma unroll
    for (int off = 32; off; off >>= 1) s += __shfl_down(s, (unsigned)off, 64);
    if (lane == 0) sr[wv] = s;
    __syncthreads();
    if (tid == 0) rowA[row] = sr[0] + sr[1] + sr[2] + sr[3];
  } else {
    const int row = blockIdx.x - M_DIM;            // w row n == B col n
    const float wmin = finv(stats[2]), wmax = finv(~stats[3]);
    const float ws = (wmax - wmin) / 255.0f;
    const float wzp = rintf(-128.0f - wmin / ws);
    const float inv_rs = 126.0f / ws;
    const float4* wr = (const float4*)(w + (size_t)row * K_DIM);
    char4* br = (char4*)(B8 + (size_t)row * K_DIM);
    char4* rr = (char4*)(R8 + (size_t)row * K_DIM);
    int sb = 0, srr = 0;
    #pragma unroll
    for (int i = 0; i < 4; ++i) {
      int idx = tid + i * 256;
      float4 t = wr[idx];
      char4 bq, rq;
      float v, qf; int q, r;
      v = t.x; qf = fminf(fmaxf(rintf(v / ws + wzp), -128.f), 127.f); q = (int)qf;
      r = (int)fminf(fmaxf(rintf((v - ws * (qf - wzp)) * inv_rs), -127.f), 127.f);
      bq.x = (signed char)q; rq.x = (signed char)r; sb += q; srr += r;
      v = t.y; qf = fminf(fmaxf(rintf(v / ws + wzp), -128.f), 127.f); q = (int)qf;
      r = (int)fminf(fmaxf(rintf((v - ws * (qf - wzp)) * inv_rs), -127.f), 127.f);
      bq.y = (signed char)q; rq.y = (signed char)r; sb += q; srr += r;
      v = t.z; qf = fminf(fmaxf(rintf(v / ws + wzp), -128.f), 127.f); q = (int)qf;
      r = (int)fminf(fmaxf(rintf((v - ws * (qf - wzp)) * inv_rs), -127.f), 127.f);
      bq.z = (signed char)q; rq.z = (signed char)r; sb += q; srr += r;
      v = t.w; qf = fminf(fmaxf(rintf(v / ws + wzp), -128.f), 127.f); q = (int)qf;
      r = (int)fminf(fmaxf(rintf((v - ws * (qf - wzp)) * inv_rs), -127.f), 127.f);
      bq.w = (signed char)q; rq.w = (signed char)r; sb += q; srr += r;
      br[idx] = bq; rr[idx] = rq;
    }
    #pragma unroll
    for (int off = 32; off; off >>= 1) {
      sb += __shfl_down(sb, (unsigned)off, 64);
      srr += __shfl_down(srr, (unsigned)off, 64);
    }
    if (lane == 0) { sr[wv] = sb; sr[4 + wv] = srr; }
    __syncthreads();
    if (tid == 0) {
      colB[row] = sr[0] + sr[1] + sr[2] + sr[3];
      colR[row] = sr[4] + sr[5] + sr[6] + sr[7];
    }
  }
}

// ---------- 3. int8 GEMM, dual chain, double-buffered 2-phase pipeline ----------
// 128x128 tile, BK=64, 8 waves (2x4), each wave 64m x 32n.
// Fragment-order LDS: band bb (16 rows x 64 K = 1KB); lane L holds
// row bb*16+(L&15), k-bytes (L>>4)*16..+15 -> glds "base+16L" lands exact.
// mfma_i32_16x16x64_i8: A[m=L&15][k=(L>>4)*16+j]; C/D col=L&15, row=(L>>4)*4+reg.
// Pipeline (T3 minimum 2-phase): STAGE(next buf) is issued BEFORE computing the
// current buf; the single __syncthreads per tile (vmcnt(0)+lgkmcnt(0)+s_barrier)
// both lands the prefetch and fences reads-before-overwrite. Load latency hides
// under the 16-MFMA+ds_read phase instead of being serially exposed.
// LDS 48KB (2x24KB): occupancy is VGPR/AGPR-capped at 2 blocks/CU anyway, so
// the extra buffer is free.
__global__ __launch_bounds__(512, 4) void gemm_i8(
    const signed char* __restrict__ A8, const signed char* __restrict__ B8,
    const signed char* __restrict__ R8,
    const int* __restrict__ rowA, const int* __restrict__ colB, const int* __restrict__ colR,
    const float* __restrict__ bias, unsigned* __restrict__ stats,
    float* __restrict__ outp) {
  __shared__ __align__(16) signed char sA[2 * 128 * 64];
  __shared__ __align__(16) signed char sB[2 * 128 * 64];
  __shared__ __align__(16) signed char sR[2 * 128 * 64];
  __shared__ unsigned s_red[2];

  const int tid = threadIdx.x;
  const int wave = tid >> 6;               // 0..7
  const int lane = tid & 63;
  // XCD-swizzle: blocks of one XCD cover 4 bn x 64 bm -> B-tile (1MB) L2-resident
  const int xcd = blockIdx.x & 7;
  const int s = blockIdx.x >> 3;           // 0..255
  const int bn = xcd * 4 + (s >> 6);
  const int bm = s & 63;
  const int rowBase = bm * 128;
  const int colBase = bn * 128;
  const int wr = wave >> 2;                // 0..1 (m half)
  const int wc = wave & 3;                 // 0..3 (n quarter)
  const int laneR = lane & 15;
  const int laneK = (lane >> 4) * 16;

  if (tid == 0) { s_red[0] = 0xFFFFFFFFu; s_red[1] = 0xFFFFFFFFu; }

  i32x4 acc_q[4][2];
  i32x4 acc_r[4][2];
  const i32x4 zero = {0, 0, 0, 0};
  #pragma unroll
  for (int i = 0; i < 4; ++i) { acc_q[i][0] = zero; acc_q[i][1] = zero;
                                acc_r[i][0] = zero; acc_r[i][1] = zero; }

  // each wave stages band bb=wave of each matrix (1KB each)
  const signed char* srcA = A8 + (size_t)(rowBase + wave * 16 + laneR) * K_DIM + laneK;
  const signed char* srcB = B8 + (size_t)(colBase + wave * 16 + laneR) * K_DIM + laneK;
  const signed char* srcR = R8 + (size_t)(colBase + wave * 16 + laneR) * K_DIM + laneK;
  signed char* dA = sA + wave * 1024 + lane * 16;
  signed char* dB = sB + wave * 1024 + lane * 16;
  signed char* dR = sR + wave * 1024 + lane * 16;

#define STAGE(b, kt) do {                        \
    async16(srcA + (kt), dA + (b) * 8192);       \
    async16(srcB + (kt), dB + (b) * 8192);       \
    async16(srcR + (kt), dR + (b) * 8192);       \
  } while (0)

#define COMPUTE(b) do {                                                        \
    i32x4 af[4];                                                               \
    _Pragma("unroll")                                                          \
    for (int mi = 0; mi < 4; ++mi)                                             \
      af[mi] = *(const i32x4*)(sA + (b) * 8192 + (wr * 4 + mi) * 1024 + lane * 16); \
    _Pragma("unroll")                                                          \
    for (int ni = 0; ni < 2; ++ni) {                                           \
      const int bo = (b) * 8192 + (wc * 2 + ni) * 1024 + lane * 16;            \
      i32x4 bf = *(const i32x4*)(sB + bo);                                     \
      i32x4 rf = *(const i32x4*)(sR + bo);                                     \
      _Pragma("unroll")                                                        \
      for (int mi = 0; mi < 4; ++mi) {                                         \
        acc_q[mi][ni] = __builtin_amdgcn_mfma_i32_16x16x64_i8(af[mi], bf, acc_q[mi][ni], 0, 0, 0); \
        acc_r[mi][ni] = __builtin_amdgcn_mfma_i32_16x16x64_i8(af[mi], rf, acc_r[mi][ni], 0, 0, 0); \
      }                                                                        \
    }                                                                          \
  } while (0)

  // prologue: land tile 0 in buf0
  STAGE(0, 0);
  __syncthreads();

  // main loop: 31 iterations x 2 tiles; prefetch next tile before computing current
  for (int kt = 0; kt < K_DIM - 128; kt += 128) {
    STAGE(1, kt + 64);
    COMPUTE(0);
    __syncthreads();
    STAGE(0, kt + 128);
    COMPUTE(1);
    __syncthreads();
  }
  // epilogue: buf0 holds tile K-128 (staged in last loop iter)
  STAGE(1, K_DIM - 64);
  COMPUTE(0);
  __syncthreads();
  COMPUTE(1);

#undef STAGE
#undef COMPUTE

  // epilogue: integer corrections (exact), write out_pre, reduce act min/max
  const float xmin = finv(stats[0]), xmax = finv(~stats[1]);
  const float xs = (xmax - xmin) / 255.0f;
  const float xzp = rintf(0.0f - xmin / xs);
  const float wmin = finv(stats[2]), wmax = finv(~stats[3]);
  const float ws = (wmax - wmin) / 255.0f;
  const float wzp = rintf(-128.0f - wmin / ws);
  const int c = 128 - (int)xzp;
  const int wzpi = (int)wzp;
  const float sw = xs * ws;
  const float xrs = xs * (ws / 126.0f);
  const int ccK = c * wzpi * K_DIM;
  unsigned kmin = 0xFFFFFFFFu, kmax = 0xFFFFFFFFu;

  int rAv[4][4];
  #pragma unroll
  for (int mi = 0; mi < 4; ++mi) {
    const int row0 = rowBase + wr * 64 + mi * 16 + (lane >> 4) * 4;
    #pragma unroll
    for (int r = 0; r < 4; ++r) rAv[mi][r] = rowA[row0 + r];
  }

  #pragma unroll
  for (int ni = 0; ni < 2; ++ni) {
    const int col = colBase + wc * 32 + ni * 16 + laneR;
    const float bv = bias[col];
    const int base_n = c * colB[col] - ccK;
    const int cR = c * colR[col];
    #pragma unroll
    for (int mi = 0; mi < 4; ++mi) {
      const int row0 = rowBase + wr * 64 + mi * 16 + (lane >> 4) * 4;
      #pragma unroll
      for (int r = 0; r < 4; ++r) {
        const int S = acc_q[mi][ni][r] + base_n - wzpi * rAv[mi][r];
        const float ov = sw * (float)S + bv;
        const int S2 = acc_r[mi][ni][r] + cR;
        const float av = ov + xrs * (float)S2;
        const unsigned k = fkey(av);
        const unsigned kf = ~k;
        kmin = kmin < k ? kmin : k;
        kmax = kmax < kf ? kmax : kf;
        outp[(size_t)(row0 + r) * N_DIM + col] = ov;
      }
    }
  }

  #pragma unroll
  for (int off = 32; off; off >>= 1) {
    unsigned t0 = __shfl_down(kmin, (unsigned)off, 64);
    unsigned t1 = __shfl_down(kmax, (unsigned)off, 64);
    kmin = kmin < t0 ? kmin : t0;
    kmax = kmax < t1 ? kmax : t1;
  }
  __syncthreads();
  if (lane == 0) { atomicMin(&s_red[0], kmin); atomicMin(&s_red[1], kmax); }
  __syncthreads();
  if (tid == 0) { atomicMin(&stats[4], s_red[0]); atomicMin(&stats[5], s_red[1]); }
}

// ---------- 4. requantize out in place ----------
__global__ void requant_kernel(float* __restrict__ out, const unsigned* __restrict__ stats, int n4) {
  const float amin = finv(stats[4]), amax = finv(~stats[5]);
  const float as = (amax - amin) / 255.0f;
  const float azp = rintf(0.0f - amin / as);
  float4* o4 = (float4*)out;
  int i0 = blockIdx.x * blockDim.x + threadIdx.x;
  int stride = gridDim.x * blockDim.x;
  for (int i = i0; i < n4; i += stride) {
    float4 t = o4[i];
    t.x = (fminf(fmaxf(rintf(t.x / as + azp), 0.f), 255.f) - azp) * as;
    t.y = (fminf(fmaxf(rintf(t.y / as + azp), 0.f), 255.f) - azp) * as;
    t.z = (fminf(fmaxf(rintf(t.z / as + azp), 0.f), 255.f) - azp) * as;
    t.w = (fminf(fmaxf(rintf(t.w / as + azp), 0.f), 255.f) - azp) * as;
    o4[i] = t;
  }
}

extern "C" void kernel_launch(void* const* d_in, const int* in_sizes, int n_in,
                              void* d_out, int out_size, void* d_ws, size_t ws_size,
                              hipStream_t stream) {
  const float* x = (const float*)d_in[0];      // [8192,4096]
  const float* w = (const float*)d_in[1];      // [4096,4096]
  const float* bias = (const float*)d_in[2];   // [4096]
  float* out = (float*)d_out;                  // [8192,4096]

  // workspace: stats | A8 32MB | B8 16MB | R8 16MB | rowA | colB | colR  (~64.1MB)
  unsigned* stats = (unsigned*)d_ws;
  signed char* A8 = (signed char*)d_ws + 256;
  signed char* B8 = A8 + (size_t)M_DIM * K_DIM;
  signed char* R8 = B8 + (size_t)N_DIM * K_DIM;
  int* rowA = (int*)(R8 + (size_t)N_DIM * K_DIM);
  int* colB = rowA + M_DIM;
  int* colR = colB + N_DIM;

  hipMemsetAsync(stats, 0xFF, 24, stream);
  minmax_fused<<<3072, 256, 0, stream>>>(x, w, stats);
  quant_fused<<<M_DIM + N_DIM, 256, 0, stream>>>(x, w, stats, A8, B8, R8, rowA, colB, colR);
  gemm_i8<<<(M_DIM / 128) * (N_DIM / 128), 512, 0, stream>>>(A8, B8, R8, rowA, colB, colR, bias, stats, out);
  requant_kernel<<<2048, 256, 0, stream>>>(out, stats, M_DIM * N_DIM / 4);
}

// Round 3
// 965.187 us; speedup vs baseline: 1.0253x; 1.0160x over previous
//
#include <hip/hip_runtime.h>
#include <stdint.h>

#define M_DIM 8192
#define N_DIM 4096
#define K_DIM 4096

typedef __attribute__((ext_vector_type(4))) int i32x4;   // i8 MFMA A/B frag (16 i8) and C/D (4 i32)

// ---------- helpers ----------
__device__ __forceinline__ unsigned fkey(float f) {
  unsigned u = __float_as_uint(f);
  return (u & 0x80000000u) ? ~u : (u | 0x80000000u);
}
__device__ __forceinline__ float finv(unsigned k) {
  return __uint_as_float((k & 0x80000000u) ? (k ^ 0x80000000u) : ~k);
}
// stats slots (all atomicMin on fkey; max stored flipped): [0]xmin [1]~xmax [2]wmin [3]~wmax [4]amin [5]~amax
__device__ __forceinline__ void async16(const void* g, void* l) {
  __builtin_amdgcn_global_load_lds(
      (const __attribute__((address_space(1))) void*)g,
      (__attribute__((address_space(3))) void*)l, 16, 0, 0);
}

// ---------- 1. fused min/max over x and w ----------
__global__ void minmax_fused(const float* __restrict__ x, const float* __restrict__ w,
                             unsigned* __restrict__ stats) {
  const bool isX = blockIdx.x < 2048;
  const float4* v4 = isX ? (const float4*)x : (const float4*)w;
  const int n4 = isX ? (M_DIM * K_DIM / 4) : (N_DIM * K_DIM / 4);
  const int bid = isX ? blockIdx.x : (blockIdx.x - 2048);
  const int nb = isX ? 2048 : 1024;
  int i0 = bid * blockDim.x + threadIdx.x;
  int stride = nb * blockDim.x;
  float vmin = 3.4e38f, vmax = -3.4e38f;
  for (int i = i0; i < n4; i += stride) {
    float4 t = v4[i];
    vmin = fminf(vmin, fminf(fminf(t.x, t.y), fminf(t.z, t.w)));
    vmax = fmaxf(vmax, fmaxf(fmaxf(t.x, t.y), fmaxf(t.z, t.w)));
  }
  unsigned kmin = fkey(vmin), kmax = ~fkey(vmax);
  #pragma unroll
  for (int off = 32; off; off >>= 1) {
    unsigned t0 = __shfl_down(kmin, (unsigned)off, 64);
    unsigned t1 = __shfl_down(kmax, (unsigned)off, 64);
    kmin = kmin < t0 ? kmin : t0;
    kmax = kmax < t1 ? kmax : t1;
  }
  if ((threadIdx.x & 63) == 0) {
    int base = isX ? 0 : 2;
    atomicMin(&stats[base + 0], kmin);
    atomicMin(&stats[base + 1], kmax);
  }
}

// ---------- 2. fused quantize, row-per-block, emits row/col sums ----------
// blocks [0,8192): x row -> A8 = q_x - 128 (i8), rowA[m] = sum_k A8
// blocks [8192,12288): w row n -> B8 = q_w (i8), R8 = round(resid*126/ws),
//                      colB[n] = sum_k B8, colR[n] = sum_k R8
__global__ void quant_fused(const float* __restrict__ x, const float* __restrict__ w,
                            const unsigned* __restrict__ stats,
                            signed char* __restrict__ A8, signed char* __restrict__ B8,
                            signed char* __restrict__ R8,
                            int* __restrict__ rowA, int* __restrict__ colB, int* __restrict__ colR) {
  __shared__ int sr[8];
  const int tid = threadIdx.x;
  const int lane = tid & 63;
  const int wv = tid >> 6;
  if (blockIdx.x < M_DIM) {
    const int row = blockIdx.x;
    const float xmin = finv(stats[0]), xmax = finv(~stats[1]);
    const float xs = (xmax - xmin) / 255.0f;
    const float xzp = rintf(0.0f - xmin / xs);
    const float4* xr = (const float4*)(x + (size_t)row * K_DIM);
    char4* ar = (char4*)(A8 + (size_t)row * K_DIM);
    int s = 0;
    #pragma unroll
    for (int i = 0; i < 4; ++i) {
      int idx = tid + i * 256;
      float4 t = xr[idx];
      int q0 = (int)(fminf(fmaxf(rintf(t.x / xs + xzp), 0.f), 255.f)) - 128;
      int q1 = (int)(fminf(fmaxf(rintf(t.y / xs + xzp), 0.f), 255.f)) - 128;
      int q2 = (int)(fminf(fmaxf(rintf(t.z / xs + xzp), 0.f), 255.f)) - 128;
      int q3 = (int)(fminf(fmaxf(rintf(t.w / xs + xzp), 0.f), 255.f)) - 128;
      char4 c4; c4.x = (signed char)q0; c4.y = (signed char)q1;
      c4.z = (signed char)q2; c4.w = (signed char)q3;
      ar[idx] = c4;
      s += q0 + q1 + q2 + q3;
    }
    #pragma unroll
    for (int off = 32; off; off >>= 1) s += __shfl_down(s, (unsigned)off, 64);
    if (lane == 0) sr[wv] = s;
    __syncthreads();
    if (tid == 0) rowA[row] = sr[0] + sr[1] + sr[2] + sr[3];
  } else {
    const int row = blockIdx.x - M_DIM;            // w row n == B col n
    const float wmin = finv(stats[2]), wmax = finv(~stats[3]);
    const float ws = (wmax - wmin) / 255.0f;
    const float wzp = rintf(-128.0f - wmin / ws);
    const float inv_rs = 126.0f / ws;
    const float4* wr = (const float4*)(w + (size_t)row * K_DIM);
    char4* br = (char4*)(B8 + (size_t)row * K_DIM);
    char4* rr = (char4*)(R8 + (size_t)row * K_DIM);
    int sb = 0, srr = 0;
    #pragma unroll
    for (int i = 0; i < 4; ++i) {
      int idx = tid + i * 256;
      float4 t = wr[idx];
      char4 bq, rq;
      float v, qf; int q, r;
      v = t.x; qf = fminf(fmaxf(rintf(v / ws + wzp), -128.f), 127.f); q = (int)qf;
      r = (int)fminf(fmaxf(rintf((v - ws * (qf - wzp)) * inv_rs), -127.f), 127.f);
      bq.x = (signed char)q; rq.x = (signed char)r; sb += q; srr += r;
      v = t.y; qf = fminf(fmaxf(rintf(v / ws + wzp), -128.f), 127.f); q = (int)qf;
      r = (int)fminf(fmaxf(rintf((v - ws * (qf - wzp)) * inv_rs), -127.f), 127.f);
      bq.y = (signed char)q; rq.y = (signed char)r; sb += q; srr += r;
      v = t.z; qf = fminf(fmaxf(rintf(v / ws + wzp), -128.f), 127.f); q = (int)qf;
      r = (int)fminf(fmaxf(rintf((v - ws * (qf - wzp)) * inv_rs), -127.f), 127.f);
      bq.z = (signed char)q; rq.z = (signed char)r; sb += q; srr += r;
      v = t.w; qf = fminf(fmaxf(rintf(v / ws + wzp), -128.f), 127.f); q = (int)qf;
      r = (int)fminf(fmaxf(rintf((v - ws * (qf - wzp)) * inv_rs), -127.f), 127.f);
      bq.w = (signed char)q; rq.w = (signed char)r; sb += q; srr += r;
      br[idx] = bq; rr[idx] = rq;
    }
    #pragma unroll
    for (int off = 32; off; off >>= 1) {
      sb += __shfl_down(sb, (unsigned)off, 64);
      srr += __shfl_down(srr, (unsigned)off, 64);
    }
    if (lane == 0) { sr[wv] = sb; sr[4 + wv] = srr; }
    __syncthreads();
    if (tid == 0) {
      colB[row] = sr[0] + sr[1] + sr[2] + sr[3];
      colR[row] = sr[4] + sr[5] + sr[6] + sr[7];
    }
  }
}

// ---------- 3. int8 GEMM, dual chain, counted-vmcnt deep pipeline (T3+T4+T5) ----------
// 128x128 tile, BK=64, 8 waves (2x4), each wave 64m x 32n.
// Fragment-order LDS: band bb (16 rows x 64 K = 1KB); lane L holds
// row bb*16+(L&15), k-bytes (L>>4)*16..+15 -> glds "base+16L" lands exact.
// mfma_i32_16x16x64_i8: A[m=L&15][k=(L>>4)*16+j]; C/D col=L&15, row=(L>>4)*4+reg.
//
// Pipeline: 3 LDS buffers, depth-2 prefetch, ONE raw s_barrier per K-step and a
// COUNTED s_waitcnt vmcnt(3) -- never vmcnt(0) in the main loop (T4, m218).
// Per iter t: {vmcnt(3) -> tile t landed (3 outstanding = tile t+1);
//              s_barrier -> visible to all waves AND all waves done reading buf(t-1);
//              STAGE tile t+2 into buf(t-1) [WAR-safe: after barrier];
//              COMPUTE tile t}.
// Tile t+2 is waited on 2 compute-phases (~1300 cy) after issue -> covers HBM miss.
// __syncthreads (vmcnt(0) drain) was the R1 null: it drained the prefetch at
// every barrier, so dbuf never overlapped (m99/m100/m233 reproduction).
// LDS 72KB: occupancy stays 2 blocks/CU (VGPR+AGPR-capped on unified file).
__global__ __launch_bounds__(512, 4) void gemm_i8(
    const signed char* __restrict__ A8, const signed char* __restrict__ B8,
    const signed char* __restrict__ R8,
    const int* __restrict__ rowA, const int* __restrict__ colB, const int* __restrict__ colR,
    const float* __restrict__ bias, unsigned* __restrict__ stats,
    float* __restrict__ outp) {
  __shared__ __align__(16) signed char sA[3 * 128 * 64];
  __shared__ __align__(16) signed char sB[3 * 128 * 64];
  __shared__ __align__(16) signed char sR[3 * 128 * 64];
  __shared__ unsigned s_red[2];

  const int tid = threadIdx.x;
  const int wave = tid >> 6;               // 0..7
  const int lane = tid & 63;
  // XCD-swizzle: blocks of one XCD cover 4 bn x 64 bm -> B-tile (1MB) L2-resident
  const int xcd = blockIdx.x & 7;
  const int s = blockIdx.x >> 3;           // 0..255
  const int bn = xcd * 4 + (s >> 6);
  const int bm = s & 63;
  const int rowBase = bm * 128;
  const int colBase = bn * 128;
  const int wr = wave >> 2;                // 0..1 (m half)
  const int wc = wave & 3;                 // 0..3 (n quarter)
  const int laneR = lane & 15;
  const int laneK = (lane >> 4) * 16;

  if (tid == 0) { s_red[0] = 0xFFFFFFFFu; s_red[1] = 0xFFFFFFFFu; }

  i32x4 acc_q[4][2];
  i32x4 acc_r[4][2];
  const i32x4 zero = {0, 0, 0, 0};
  #pragma unroll
  for (int i = 0; i < 4; ++i) { acc_q[i][0] = zero; acc_q[i][1] = zero;
                                acc_r[i][0] = zero; acc_r[i][1] = zero; }

  // each wave stages band bb=wave of each matrix (1KB each)
  const signed char* srcA = A8 + (size_t)(rowBase + wave * 16 + laneR) * K_DIM + laneK;
  const signed char* srcB = B8 + (size_t)(colBase + wave * 16 + laneR) * K_DIM + laneK;
  const signed char* srcR = R8 + (size_t)(colBase + wave * 16 + laneR) * K_DIM + laneK;
  signed char* dA = sA + wave * 1024 + lane * 16;
  signed char* dB = sB + wave * 1024 + lane * 16;
  signed char* dR = sR + wave * 1024 + lane * 16;

#define STAGE(off, kt) do {                      \
    async16(srcA + (kt), dA + (off));            \
    async16(srcB + (kt), dB + (off));            \
    async16(srcR + (kt), dR + (off));            \
  } while (0)

#define COMPUTE(off) do {                                                      \
    i32x4 af[4];                                                               \
    _Pragma("unroll")                                                          \
    for (int mi = 0; mi < 4; ++mi)                                             \
      af[mi] = *(const i32x4*)(sA + (off) + (wr * 4 + mi) * 1024 + lane * 16); \
    i32x4 bf[2], rf[2];                                                        \
    _Pragma("unroll")                                                          \
    for (int ni = 0; ni < 2; ++ni) {                                           \
      const int bo = (off) + (wc * 2 + ni) * 1024 + lane * 16;                 \
      bf[ni] = *(const i32x4*)(sB + bo);                                       \
      rf[ni] = *(const i32x4*)(sR + bo);                                       \
    }                                                                          \
    __builtin_amdgcn_s_setprio(1);                                             \
    _Pragma("unroll")                                                          \
    for (int ni = 0; ni < 2; ++ni) {                                           \
      _Pragma("unroll")                                                        \
      for (int mi = 0; mi < 4; ++mi) {                                         \
        acc_q[mi][ni] = __builtin_amdgcn_mfma_i32_16x16x64_i8(af[mi], bf[ni], acc_q[mi][ni], 0, 0, 0); \
        acc_r[mi][ni] = __builtin_amdgcn_mfma_i32_16x16x64_i8(af[mi], rf[ni], acc_r[mi][ni], 0, 0, 0); \
      }                                                                        \
    }                                                                          \
    __builtin_amdgcn_s_setprio(0);                                             \
  } while (0)

  // prologue: issue tiles 0 and 1 (6 loads in flight per wave)
  STAGE(0, 0);
  STAGE(8192, 64);

  int o0 = 0, o1 = 8192, o2 = 16384;   // o0=compute, o1=next, o2=stage target

  // main loop: tiles 0..61; counted vmcnt, 1 barrier per K-step
  for (int t = 0; t < 62; ++t) {
    asm volatile("s_waitcnt vmcnt(3)" ::: "memory");
    __builtin_amdgcn_s_barrier();
    STAGE(o2, (t + 2) * 64);
    COMPUTE(o0);
    int tmp = o0; o0 = o1; o1 = o2; o2 = tmp;
  }
  // tile 62: tile 63 still in flight -> vmcnt(3)
  asm volatile("s_waitcnt vmcnt(3)" ::: "memory");
  __builtin_amdgcn_s_barrier();
  COMPUTE(o0);
  { int tmp = o0; o0 = o1; o1 = o2; o2 = tmp; }
  // tile 63: nothing beyond it -> full drain
  asm volatile("s_waitcnt vmcnt(0)" ::: "memory");
  __builtin_amdgcn_s_barrier();
  COMPUTE(o0);

#undef STAGE
#undef COMPUTE

  // epilogue: integer corrections (exact), write out_pre, reduce act min/max
  const float xmin = finv(stats[0]), xmax = finv(~stats[1]);
  const float xs = (xmax - xmin) / 255.0f;
  const float xzp = rintf(0.0f - xmin / xs);
  const float wmin = finv(stats[2]), wmax = finv(~stats[3]);
  const float ws = (wmax - wmin) / 255.0f;
  const float wzp = rintf(-128.0f - wmin / ws);
  const int c = 128 - (int)xzp;
  const int wzpi = (int)wzp;
  const float sw = xs * ws;
  const float xrs = xs * (ws / 126.0f);
  const int ccK = c * wzpi * K_DIM;
  unsigned kmin = 0xFFFFFFFFu, kmax = 0xFFFFFFFFu;

  int rAv[4][4];
  #pragma unroll
  for (int mi = 0; mi < 4; ++mi) {
    const int row0 = rowBase + wr * 64 + mi * 16 + (lane >> 4) * 4;
    #pragma unroll
    for (int r = 0; r < 4; ++r) rAv[mi][r] = rowA[row0 + r];
  }

  #pragma unroll
  for (int ni = 0; ni < 2; ++ni) {
    const int col = colBase + wc * 32 + ni * 16 + laneR;
    const float bv = bias[col];
    const int base_n = c * colB[col] - ccK;
    const int cR = c * colR[col];
    #pragma unroll
    for (int mi = 0; mi < 4; ++mi) {
      const int row0 = rowBase + wr * 64 + mi * 16 + (lane >> 4) * 4;
      #pragma unroll
      for (int r = 0; r < 4; ++r) {
        const int S = acc_q[mi][ni][r] + base_n - wzpi * rAv[mi][r];
        const float ov = sw * (float)S + bv;
        const int S2 = acc_r[mi][ni][r] + cR;
        const float av = ov + xrs * (float)S2;
        const unsigned k = fkey(av);
        const unsigned kf = ~k;
        kmin = kmin < k ? kmin : k;
        kmax = kmax < kf ? kmax : kf;
        outp[(size_t)(row0 + r) * N_DIM + col] = ov;
      }
    }
  }

  #pragma unroll
  for (int off = 32; off; off >>= 1) {
    unsigned t0 = __shfl_down(kmin, (unsigned)off, 64);
    unsigned t1 = __shfl_down(kmax, (unsigned)off, 64);
    kmin = kmin < t0 ? kmin : t0;
    kmax = kmax < t1 ? kmax : t1;
  }
  __syncthreads();
  if (lane == 0) { atomicMin(&s_red[0], kmin); atomicMin(&s_red[1], kmax); }
  __syncthreads();
  if (tid == 0) { atomicMin(&stats[4], s_red[0]); atomicMin(&stats[5], s_red[1]); }
}

// ---------- 4. requantize out in place ----------
__global__ void requant_kernel(float* __restrict__ out, const unsigned* __restrict__ stats, int n4) {
  const float amin = finv(stats[4]), amax = finv(~stats[5]);
  const float as = (amax - amin) / 255.0f;
  const float azp = rintf(0.0f - amin / as);
  float4* o4 = (float4*)out;
  int i0 = blockIdx.x * blockDim.x + threadIdx.x;
  int stride = gridDim.x * blockDim.x;
  for (int i = i0; i < n4; i += stride) {
    float4 t = o4[i];
    t.x = (fminf(fmaxf(rintf(t.x / as + azp), 0.f), 255.f) - azp) * as;
    t.y = (fminf(fmaxf(rintf(t.y / as + azp), 0.f), 255.f) - azp) * as;
    t.z = (fminf(fmaxf(rintf(t.z / as + azp), 0.f), 255.f) - azp) * as;
    t.w = (fminf(fmaxf(rintf(t.w / as + azp), 0.f), 255.f) - azp) * as;
    o4[i] = t;
  }
}

extern "C" void kernel_launch(void* const* d_in, const int* in_sizes, int n_in,
                              void* d_out, int out_size, void* d_ws, size_t ws_size,
                              hipStream_t stream) {
  const float* x = (const float*)d_in[0];      // [8192,4096]
  const float* w = (const float*)d_in[1];      // [4096,4096]
  const float* bias = (const float*)d_in[2];   // [4096]
  float* out = (float*)d_out;                  // [8192,4096]

  // workspace: stats | A8 32MB | B8 16MB | R8 16MB | rowA | colB | colR  (~64.1MB)
  unsigned* stats = (unsigned*)d_ws;
  signed char* A8 = (signed char*)d_ws + 256;
  signed char* B8 = A8 + (size_t)M_DIM * K_DIM;
  signed char* R8 = B8 + (size_t)N_DIM * K_DIM;
  int* rowA = (int*)(R8 + (size_t)N_DIM * K_DIM);
  int* colB = rowA + M_DIM;
  int* colR = colB + N_DIM;

  hipMemsetAsync(stats, 0xFF, 24, stream);
  minmax_fused<<<3072, 256, 0, stream>>>(x, w, stats);
  quant_fused<<<M_DIM + N_DIM, 256, 0, stream>>>(x, w, stats, A8, B8, R8, rowA, colB, colR);
  gemm_i8<<<(M_DIM / 128) * (N_DIM / 128), 512, 0, stream>>>(A8, B8, R8, rowA, colB, colR, bias, stats, out);
  requant_kernel<<<2048, 256, 0, stream>>>(out, stats, M_DIM * N_DIM / 4);
}

// Round 4
// 958.076 us; speedup vs baseline: 1.0329x; 1.0074x over previous
//
#include <hip/hip_runtime.h>
#include <hip/hip_cooperative_groups.h>
#include <stdint.h>

namespace cg = cooperative_groups;

#define M_DIM 8192
#define N_DIM 4096
#define K_DIM 4096

typedef __attribute__((ext_vector_type(4))) int i32x4;   // i8 MFMA A/B frag (16 i8) and C/D (4 i32)

// ---------- helpers ----------
__device__ __forceinline__ unsigned fkey(float f) {
  unsigned u = __float_as_uint(f);
  return (u & 0x80000000u) ? ~u : (u | 0x80000000u);
}
__device__ __forceinline__ float finv(unsigned k) {
  return __uint_as_float((k & 0x80000000u) ? (k ^ 0x80000000u) : ~k);
}
// stats slots (all atomicMin on fkey; max stored flipped): [0]xmin [1]~xmax [2]wmin [3]~wmax [4]amin [5]~amax
__device__ __forceinline__ void async16(const void* g, void* l) {
  __builtin_amdgcn_global_load_lds(
      (const __attribute__((address_space(1))) void*)g,
      (__attribute__((address_space(3))) void*)l, 16, 0, 0);
}

// ---------- 1. fused min/max + quantize (cooperative, grid-synced) ----------
// phase 1: grid-stride min/max over x and w -> stats[0..3] via atomicMin(fkey)
// grid.sync()
// phase 2: 12 rows per block:
//   r<8:  x row (blockIdx + r*1024) -> A8 = q_x - 128 (i8), rowA = sum
//   r>=8: w row -> B8 = q_w (i8), R8 = round(resid*126/ws), colB/colR sums
__global__ __launch_bounds__(256, 4) void minmax_quant(
    const float* __restrict__ x, const float* __restrict__ w,
    unsigned* __restrict__ stats,
    signed char* __restrict__ A8, signed char* __restrict__ B8,
    signed char* __restrict__ R8,
    int* __restrict__ rowA, int* __restrict__ colB, int* __restrict__ colR) {
  __shared__ int sr[8];
  const int tid = threadIdx.x;
  const int lane = tid & 63;
  const int wv = tid >> 6;

  // ---- phase 1: minmax ----
  {
    const float4* x4 = (const float4*)x;
    const float4* w4 = (const float4*)w;
    const int n4x = M_DIM * K_DIM / 4;
    const int n4w = N_DIM * K_DIM / 4;
    const int i0 = blockIdx.x * 256 + tid;
    const int stride = 1024 * 256;
    float xmn = 3.4e38f, xmx = -3.4e38f, wmn = 3.4e38f, wmx = -3.4e38f;
    for (int i = i0; i < n4x; i += stride) {
      float4 t = x4[i];
      xmn = fminf(xmn, fminf(fminf(t.x, t.y), fminf(t.z, t.w)));
      xmx = fmaxf(xmx, fmaxf(fmaxf(t.x, t.y), fmaxf(t.z, t.w)));
    }
    for (int i = i0; i < n4w; i += stride) {
      float4 t = w4[i];
      wmn = fminf(wmn, fminf(fminf(t.x, t.y), fminf(t.z, t.w)));
      wmx = fmaxf(wmx, fmaxf(fmaxf(t.x, t.y), fmaxf(t.z, t.w)));
    }
    unsigned k0 = fkey(xmn), k1 = ~fkey(xmx), k2 = fkey(wmn), k3 = ~fkey(wmx);
    #pragma unroll
    for (int off = 32; off; off >>= 1) {
      unsigned t0 = __shfl_down(k0, (unsigned)off, 64);
      unsigned t1 = __shfl_down(k1, (unsigned)off, 64);
      unsigned t2 = __shfl_down(k2, (unsigned)off, 64);
      unsigned t3 = __shfl_down(k3, (unsigned)off, 64);
      k0 = k0 < t0 ? k0 : t0;  k1 = k1 < t1 ? k1 : t1;
      k2 = k2 < t2 ? k2 : t2;  k3 = k3 < t3 ? k3 : t3;
    }
    if (lane == 0) {
      atomicMin(&stats[0], k0);
      atomicMin(&stats[1], k1);
      atomicMin(&stats[2], k2);
      atomicMin(&stats[3], k3);
    }
  }

  cg::this_grid().sync();

  // ---- phase 2: quantize ----
  const float xmin = finv(stats[0]), xmax = finv(~stats[1]);
  const float xs = (xmax - xmin) / 255.0f;
  const float xzp = rintf(0.0f - xmin / xs);
  const float wmin = finv(stats[2]), wmax = finv(~stats[3]);
  const float ws = (wmax - wmin) / 255.0f;
  const float wzp = rintf(-128.0f - wmin / ws);
  const float inv_rs = 126.0f / ws;

  for (int r = 0; r < 12; ++r) {
    if (r < 8) {
      const int row = blockIdx.x + r * 1024;          // x row
      const float4* xr = (const float4*)(x + (size_t)row * K_DIM);
      char4* ar = (char4*)(A8 + (size_t)row * K_DIM);
      int s = 0;
      #pragma unroll
      for (int i = 0; i < 4; ++i) {
        int idx = tid + i * 256;
        float4 t = xr[idx];
        int q0 = (int)(fminf(fmaxf(rintf(t.x / xs + xzp), 0.f), 255.f)) - 128;
        int q1 = (int)(fminf(fmaxf(rintf(t.y / xs + xzp), 0.f), 255.f)) - 128;
        int q2 = (int)(fminf(fmaxf(rintf(t.z / xs + xzp), 0.f), 255.f)) - 128;
        int q3 = (int)(fminf(fmaxf(rintf(t.w / xs + xzp), 0.f), 255.f)) - 128;
        char4 c4; c4.x = (signed char)q0; c4.y = (signed char)q1;
        c4.z = (signed char)q2; c4.w = (signed char)q3;
        ar[idx] = c4;
        s += q0 + q1 + q2 + q3;
      }
      #pragma unroll
      for (int off = 32; off; off >>= 1) s += __shfl_down(s, (unsigned)off, 64);
      if (lane == 0) sr[wv] = s;
      __syncthreads();
      if (tid == 0) rowA[row] = sr[0] + sr[1] + sr[2] + sr[3];
      __syncthreads();
    } else {
      const int row = blockIdx.x + (r - 8) * 1024;    // w row n == B col n
      const float4* wr = (const float4*)(w + (size_t)row * K_DIM);
      char4* br = (char4*)(B8 + (size_t)row * K_DIM);
      char4* rr = (char4*)(R8 + (size_t)row * K_DIM);
      int sb = 0, srr = 0;
      #pragma unroll
      for (int i = 0; i < 4; ++i) {
        int idx = tid + i * 256;
        float4 t = wr[idx];
        char4 bq, rq;
        float v, qf; int q, rv;
        v = t.x; qf = fminf(fmaxf(rintf(v / ws + wzp), -128.f), 127.f); q = (int)qf;
        rv = (int)fminf(fmaxf(rintf((v - ws * (qf - wzp)) * inv_rs), -127.f), 127.f);
        bq.x = (signed char)q; rq.x = (signed char)rv; sb += q; srr += rv;
        v = t.y; qf = fminf(fmaxf(rintf(v / ws + wzp), -128.f), 127.f); q = (int)qf;
        rv = (int)fminf(fmaxf(rintf((v - ws * (qf - wzp)) * inv_rs), -127.f), 127.f);
        bq.y = (signed char)q; rq.y = (signed char)rv; sb += q; srr += rv;
        v = t.z; qf = fminf(fmaxf(rintf(v / ws + wzp), -128.f), 127.f); q = (int)qf;
        rv = (int)fminf(fmaxf(rintf((v - ws * (qf - wzp)) * inv_rs), -127.f), 127.f);
        bq.z = (signed char)q; rq.z = (signed char)rv; sb += q; srr += rv;
        v = t.w; qf = fminf(fmaxf(rintf(v / ws + wzp), -128.f), 127.f); q = (int)qf;
        rv = (int)fminf(fmaxf(rintf((v - ws * (qf - wzp)) * inv_rs), -127.f), 127.f);
        bq.w = (signed char)q; rq.w = (signed char)rv; sb += q; srr += rv;
        br[idx] = bq; rr[idx] = rq;
      }
      #pragma unroll
      for (int off = 32; off; off >>= 1) {
        sb += __shfl_down(sb, (unsigned)off, 64);
        srr += __shfl_down(srr, (unsigned)off, 64);
      }
      if (lane == 0) { sr[wv] = sb; sr[4 + wv] = srr; }
      __syncthreads();
      if (tid == 0) {
        colB[row] = sr[0] + sr[1] + sr[2] + sr[3];
        colR[row] = sr[4] + sr[5] + sr[6] + sr[7];
      }
      __syncthreads();
    }
  }
}

// ---------- 2. int8 GEMM, dual chain, counted-vmcnt pipeline, unroll-3 ----------
// 128x128 tile, BK=64, 8 waves (2x4), each wave 64m x 32n.
// Fragment-order LDS: band bb (16 rows x 64 K = 1KB); lane L holds
// row bb*16+(L&15), k-bytes (L>>4)*16..+15 -> glds "base+16L" lands exact.
// mfma_i32_16x16x64_i8: A[m=L&15][k=(L>>4)*16+j]; C/D col=L&15, row=(L>>4)*4+reg.
//
// Schedule identical to R3 (verified): 3 LDS buffers, depth-2 prefetch, ONE raw
// s_barrier per K-step, counted s_waitcnt vmcnt(3) (never 0 in main loop).
// New: manual unroll x3 so every ds_read address is a single vaddr + literal
// offset immediate (kills per-iter address VALU) and staging advances by one
// pointer bump per triple.
__global__ __launch_bounds__(512, 4) void gemm_i8(
    const signed char* __restrict__ A8, const signed char* __restrict__ B8,
    const signed char* __restrict__ R8,
    const int* __restrict__ rowA, const int* __restrict__ colB, const int* __restrict__ colR,
    const float* __restrict__ bias, unsigned* __restrict__ stats,
    float* __restrict__ outp) {
  __shared__ __align__(16) signed char sA[3 * 128 * 64];
  __shared__ __align__(16) signed char sB[3 * 128 * 64];
  __shared__ __align__(16) signed char sR[3 * 128 * 64];
  __shared__ unsigned s_red[2];

  const int tid = threadIdx.x;
  const int wave = tid >> 6;               // 0..7
  const int lane = tid & 63;
  // XCD-swizzle: blocks of one XCD cover 4 bn x 64 bm -> B-tile (1MB) L2-resident
  const int xcd = blockIdx.x & 7;
  const int s = blockIdx.x >> 3;           // 0..255
  const int bn = xcd * 4 + (s >> 6);
  const int bm = s & 63;
  const int rowBase = bm * 128;
  const int colBase = bn * 128;
  const int wr = wave >> 2;                // 0..1 (m half)
  const int wc = wave & 3;                 // 0..3 (n quarter)
  const int laneR = lane & 15;
  const int laneK = (lane >> 4) * 16;

  if (tid == 0) { s_red[0] = 0xFFFFFFFFu; s_red[1] = 0xFFFFFFFFu; }

  i32x4 acc_q[4][2];
  i32x4 acc_r[4][2];
  const i32x4 zero = {0, 0, 0, 0};
  #pragma unroll
  for (int i = 0; i < 4; ++i) { acc_q[i][0] = zero; acc_q[i][1] = zero;
                                acc_r[i][0] = zero; acc_r[i][1] = zero; }

  // each wave stages band bb=wave of each matrix (1KB each)
  const signed char* pA = A8 + (size_t)(rowBase + wave * 16 + laneR) * K_DIM + laneK;
  const signed char* pB = B8 + (size_t)(colBase + wave * 16 + laneR) * K_DIM + laneK;
  const signed char* pR = R8 + (size_t)(colBase + wave * 16 + laneR) * K_DIM + laneK;
  signed char* dA = sA + wave * 1024 + lane * 16;
  signed char* dB = sB + wave * 1024 + lane * 16;
  signed char* dR = sR + wave * 1024 + lane * 16;

#define STAGE(SO, GO) do {                       \
    async16(pA + (GO), dA + (SO));               \
    async16(pB + (GO), dB + (SO));               \
    async16(pR + (GO), dR + (SO));               \
  } while (0)

#define COMPUTE(OFF) do {                                                      \
    i32x4 af[4];                                                               \
    _Pragma("unroll")                                                          \
    for (int mi = 0; mi < 4; ++mi)                                             \
      af[mi] = *(const i32x4*)(sA + (OFF) + (wr * 4 + mi) * 1024 + lane * 16); \
    i32x4 bf[2], rf[2];                                                        \
    _Pragma("unroll")                                                          \
    for (int ni = 0; ni < 2; ++ni) {                                           \
      const int bo = (OFF) + (wc * 2 + ni) * 1024 + lane * 16;                 \
      bf[ni] = *(const i32x4*)(sB + bo);                                       \
      rf[ni] = *(const i32x4*)(sR + bo);                                       \
    }                                                                          \
    __builtin_amdgcn_s_setprio(1);                                             \
    _Pragma("unroll")                                                          \
    for (int ni = 0; ni < 2; ++ni) {                                           \
      _Pragma("unroll")                                                        \
      for (int mi = 0; mi < 4; ++mi) {                                         \
        acc_q[mi][ni] = __builtin_amdgcn_mfma_i32_16x16x64_i8(af[mi], bf[ni], acc_q[mi][ni], 0, 0, 0); \
        acc_r[mi][ni] = __builtin_amdgcn_mfma_i32_16x16x64_i8(af[mi], rf[ni], acc_r[mi][ni], 0, 0, 0); \
      }                                                                        \
    }                                                                          \
    __builtin_amdgcn_s_setprio(0);                                             \
  } while (0)

#define STEP(CO, SO, GO) do {                            \
    asm volatile("s_waitcnt vmcnt(3)" ::: "memory");     \
    __builtin_amdgcn_s_barrier();                        \
    STAGE(SO, GO);                                       \
    COMPUTE(CO);                                         \
  } while (0)

  // prologue: issue tiles 0 and 1 (6 loads in flight per wave)
  STAGE(0, 0);
  STAGE(8192, 64);

  // main loop: 20 triples compute tiles 0..59, staging 2..61 (pA tracks t*64)
  for (int t3 = 0; t3 < 20; ++t3) {
    STEP(0,     16384, 128);
    STEP(8192,  0,     192);
    STEP(16384, 8192,  256);
    pA += 192; pB += 192; pR += 192;
  }
  // tiles 60, 61 (stage 62, 63)
  STEP(0,    16384, 128);
  STEP(8192, 0,     192);
  // tile 62: tile 63 still in flight -> vmcnt(3)
  asm volatile("s_waitcnt vmcnt(3)" ::: "memory");
  __builtin_amdgcn_s_barrier();
  COMPUTE(16384);
  // tile 63: nothing beyond it -> full drain
  asm volatile("s_waitcnt vmcnt(0)" ::: "memory");
  __builtin_amdgcn_s_barrier();
  COMPUTE(0);

#undef STEP
#undef STAGE
#undef COMPUTE

  // epilogue: integer corrections (exact), write out_pre, reduce act min/max
  const float xmin = finv(stats[0]), xmax = finv(~stats[1]);
  const float xs = (xmax - xmin) / 255.0f;
  const float xzp = rintf(0.0f - xmin / xs);
  const float wmin = finv(stats[2]), wmax = finv(~stats[3]);
  const float ws = (wmax - wmin) / 255.0f;
  const float wzp = rintf(-128.0f - wmin / ws);
  const int c = 128 - (int)xzp;
  const int wzpi = (int)wzp;
  const float sw = xs * ws;
  const float xrs = xs * (ws / 126.0f);
  const int ccK = c * wzpi * K_DIM;
  unsigned kmin = 0xFFFFFFFFu, kmax = 0xFFFFFFFFu;

  int rAv[4][4];
  #pragma unroll
  for (int mi = 0; mi < 4; ++mi) {
    const int row0 = rowBase + wr * 64 + mi * 16 + (lane >> 4) * 4;
    #pragma unroll
    for (int r = 0; r < 4; ++r) rAv[mi][r] = rowA[row0 + r];
  }

  #pragma unroll
  for (int ni = 0; ni < 2; ++ni) {
    const int col = colBase + wc * 32 + ni * 16 + laneR;
    const float bv = bias[col];
    const int base_n = c * colB[col] - ccK;
    const int cR = c * colR[col];
    #pragma unroll
    for (int mi = 0; mi < 4; ++mi) {
      const int row0 = rowBase + wr * 64 + mi * 16 + (lane >> 4) * 4;
      #pragma unroll
      for (int r = 0; r < 4; ++r) {
        const int S = acc_q[mi][ni][r] + base_n - wzpi * rAv[mi][r];
        const float ov = sw * (float)S + bv;
        const int S2 = acc_r[mi][ni][r] + cR;
        const float av = ov + xrs * (float)S2;
        const unsigned k = fkey(av);
        const unsigned kf = ~k;
        kmin = kmin < k ? kmin : k;
        kmax = kmax < kf ? kmax : kf;
        outp[(size_t)(row0 + r) * N_DIM + col] = ov;
      }
    }
  }

  #pragma unroll
  for (int off = 32; off; off >>= 1) {
    unsigned t0 = __shfl_down(kmin, (unsigned)off, 64);
    unsigned t1 = __shfl_down(kmax, (unsigned)off, 64);
    kmin = kmin < t0 ? kmin : t0;
    kmax = kmax < t1 ? kmax : t1;
  }
  __syncthreads();
  if (lane == 0) { atomicMin(&s_red[0], kmin); atomicMin(&s_red[1], kmax); }
  __syncthreads();
  if (tid == 0) { atomicMin(&stats[4], s_red[0]); atomicMin(&stats[5], s_red[1]); }
}

// ---------- 3. requantize out in place ----------
__global__ void requant_kernel(float* __restrict__ out, const unsigned* __restrict__ stats, int n4) {
  const float amin = finv(stats[4]), amax = finv(~stats[5]);
  const float as = (amax - amin) / 255.0f;
  const float azp = rintf(0.0f - amin / as);
  float4* o4 = (float4*)out;
  int i0 = blockIdx.x * blockDim.x + threadIdx.x;
  int stride = gridDim.x * blockDim.x;
  for (int i = i0; i < n4; i += stride) {
    float4 t = o4[i];
    t.x = (fminf(fmaxf(rintf(t.x / as + azp), 0.f), 255.f) - azp) * as;
    t.y = (fminf(fmaxf(rintf(t.y / as + azp), 0.f), 255.f) - azp) * as;
    t.z = (fminf(fmaxf(rintf(t.z / as + azp), 0.f), 255.f) - azp) * as;
    t.w = (fminf(fmaxf(rintf(t.w / as + azp), 0.f), 255.f) - azp) * as;
    o4[i] = t;
  }
}

extern "C" void kernel_launch(void* const* d_in, const int* in_sizes, int n_in,
                              void* d_out, int out_size, void* d_ws, size_t ws_size,
                              hipStream_t stream) {
  const float* x = (const float*)d_in[0];      // [8192,4096]
  const float* w = (const float*)d_in[1];      // [4096,4096]
  const float* bias = (const float*)d_in[2];   // [4096]
  float* out = (float*)d_out;                  // [8192,4096]

  // workspace: stats | A8 32MB | B8 16MB | R8 16MB | rowA | colB | colR  (~64.1MB)
  unsigned* stats = (unsigned*)d_ws;
  signed char* A8 = (signed char*)d_ws + 256;
  signed char* B8 = A8 + (size_t)M_DIM * K_DIM;
  signed char* R8 = B8 + (size_t)N_DIM * K_DIM;
  int* rowA = (int*)(R8 + (size_t)N_DIM * K_DIM);
  int* colB = rowA + M_DIM;
  int* colR = colB + N_DIM;

  hipMemsetAsync(stats, 0xFF, 24, stream);

  void* kargs[] = {(void*)&x, (void*)&w, (void*)&stats, (void*)&A8, (void*)&B8,
                   (void*)&R8, (void*)&rowA, (void*)&colB, (void*)&colR};
  hipLaunchCooperativeKernel((void*)minmax_quant, dim3(1024), dim3(256), kargs, 0, stream);

  gemm_i8<<<(M_DIM / 128) * (N_DIM / 128), 512, 0, stream>>>(A8, B8, R8, rowA, colB, colR, bias, stats, out);
  requant_kernel<<<2048, 256, 0, stream>>>(out, stats, M_DIM * N_DIM / 4);
}